// Round 5
// baseline (2840.215 us; speedup 1.0000x reference)
//
#include <hip/hip_runtime.h>
#include <hip/hip_bf16.h>
#include <cstdint>
#include <cstddef>

// ---------------------------------------------------------------------------
// BiLSTM-CRF forward on MI355X.
// gather(emb) -> cast weights -> MFMA GEMM (x@Wih^T+bias, fragment order) ->
// persistent 512-step LSTM (per-WAVE flag barrier through LLC) -> emissions
// -> CRF -> loss.
// r5 vs r4: step-body reorder for vmcnt FIFO semantics — XWr prefetch issues
// at the TOP of the iteration (hidden behind h-load wait + MFMA, ~2000 cy
// before the poll), hs history store shares the hg drain. r4's poll was
// inadvertently waiting on the HBM prefetch every step (vmcnt(0) is FIFO-
// inclusive), putting ~1000+ cy of HBM latency inside the barrier.
// ---------------------------------------------------------------------------

typedef __attribute__((ext_vector_type(4))) float f32x4;
typedef __attribute__((ext_vector_type(8))) short bf16x8;

#define DEVINL __device__ __forceinline__

// ---- workspace layout (bytes) ----
static constexpr size_t XWR_OFF  = 0;            // 268,435,456  (S,dir,slot,g,wv,lane,reg) bf16
static constexpr size_t X_OFF    = 268435456;    //  33,554,432  x bf16 (reused: tags+loss after gemm)
static constexpr size_t HS_OFF   = 301989888;    //  67,108,864  hs bf16 (512 x 64 x 1024)
static constexpr size_t WIH_OFF  = 369098752;    //   4,194,304  Wih cat bf16 (4096 x 512)
static constexpr size_t WHH_OFF  = 373293056;    //   4,194,304  Whh cat bf16 (4096 x 512)
static constexpr size_t BIAS_OFF = 377487360;    //      16,384  bias f32 (4096)
static constexpr size_t H_OFF    = 377503744;    //     262,144  h bf16 [2buf][2dir][32slot][64row][16u]
static constexpr size_t EM_OFF   = 377765888;    //   1,179,648  em f32 [64][512][9]
// total: 378,945,536 B

DEVINL unsigned short f2bf(float f) {
  unsigned u = __builtin_bit_cast(unsigned, f);
  unsigned r = u + 0x7fffu + ((u >> 16) & 1u);
  return (unsigned short)(r >> 16);
}
DEVINL float bf2f(unsigned int h) {
  unsigned u = (h & 0xffffu) << 16;
  return __builtin_bit_cast(float, u);
}
DEVINL bf16x8 as_bf16x8(uint4 v) { return __builtin_bit_cast(bf16x8, v); }

DEVINL float fsigmoid(float x) {
  const float e = exp2f(-1.4426950408889634f * x);
  return __builtin_amdgcn_rcpf(1.f + e);
}
DEVINL float ftanh(float x) {
  const float e = exp2f(2.8853900817779268f * x);
  return 1.f - 2.f * __builtin_amdgcn_rcpf(e + 1.f);
}
DEVINL float selbf(uint2 v, int r) {
  const unsigned u = (r < 2) ? v.x : v.y;
  return bf2f((r & 1) ? (u >> 16) : u);
}

// ---------------------------------------------------------------------------
// 1) embedding gather
// ---------------------------------------------------------------------------
__global__ void k_gather(const int* __restrict__ sent, const float* __restrict__ emb,
                         unsigned short* __restrict__ x) {
  const int m = blockIdx.x;            // 0..32767 = s*64+b
  const int s = m >> 6, b = m & 63;
  const int tok = sent[b * 512 + s];
  const float4 v = ((const float4*)(emb + (size_t)tok * 512))[threadIdx.x];
  uint2 o;
  o.x = (unsigned)f2bf(v.x) | ((unsigned)f2bf(v.y) << 16);
  o.y = (unsigned)f2bf(v.z) | ((unsigned)f2bf(v.w) << 16);
  ((uint2*)(x + (size_t)m * 512))[threadIdx.x] = o;
}

// ---------------------------------------------------------------------------
// 2) weight cast/concat
// ---------------------------------------------------------------------------
__global__ void k_prep(const float* __restrict__ wihf, const float* __restrict__ whhf,
                       const float* __restrict__ bihf, const float* __restrict__ bhhf,
                       const float* __restrict__ wihb, const float* __restrict__ whhb,
                       const float* __restrict__ bihb, const float* __restrict__ bhhb,
                       unsigned short* __restrict__ Wih, unsigned short* __restrict__ Whh,
                       float* __restrict__ bias) {
  const int n = blockIdx.x;
  const int dir = n >> 11, r = n & 2047;
  const float* wi = dir ? wihb : wihf;
  const float* wh = dir ? whhb : whhf;
  const float4 a = ((const float4*)(wi + (size_t)r * 512))[threadIdx.x];
  const float4 c = ((const float4*)(wh + (size_t)r * 512))[threadIdx.x];
  uint2 oa, oc;
  oa.x = (unsigned)f2bf(a.x) | ((unsigned)f2bf(a.y) << 16);
  oa.y = (unsigned)f2bf(a.z) | ((unsigned)f2bf(a.w) << 16);
  oc.x = (unsigned)f2bf(c.x) | ((unsigned)f2bf(c.y) << 16);
  oc.y = (unsigned)f2bf(c.z) | ((unsigned)f2bf(c.w) << 16);
  ((uint2*)(Wih + (size_t)n * 512))[threadIdx.x] = oa;
  ((uint2*)(Whh + (size_t)n * 512))[threadIdx.x] = oc;
  if (threadIdx.x == 0)
    bias[n] = dir ? (bihb[r] + bhhb[r]) : (bihf[r] + bhhf[r]);
}

// ---------------------------------------------------------------------------
// 3) h0 -> bf16 into hg buf0, layout [dir][slot][row][16], write-through u64
// ---------------------------------------------------------------------------
__global__ void k_inith(const float* __restrict__ h0, unsigned short* __restrict__ hg) {
  const int gi = blockIdx.x * 256 + threadIdx.x;   // 16384 chunks of 4 units
  const int dir = gi >> 13, rem = gi & 8191;
  const int row = rem >> 7, c = rem & 127;         // 128 chunks per row
  const int slot = c >> 2, off = (c & 3) * 4;
  const float4 v = *(const float4*)(h0 + ((size_t)(dir * 64 + row)) * 512 + slot * 16 + off);
  const unsigned long long p =
      (unsigned long long)f2bf(v.x) | ((unsigned long long)f2bf(v.y) << 16) |
      ((unsigned long long)f2bf(v.z) << 32) | ((unsigned long long)f2bf(v.w) << 48);
  __hip_atomic_store(
      (unsigned long long*)(hg + (((size_t)dir * 32 + slot) * 64 + row) * 16 + off),
      p, __ATOMIC_RELAXED, __HIP_MEMORY_SCOPE_AGENT);
}

// ---------------------------------------------------------------------------
// 4) GEMM: M=32768 N=4096 K=512, 128x128 tiles, global_load_lds(16B),
//    XOR-swizzled LDS. Output bf16 in MFMA-fragment order.
// ---------------------------------------------------------------------------
typedef __attribute__((address_space(1))) const unsigned int* as1c_u32p;
typedef __attribute__((address_space(3))) unsigned int* as3_u32p;

DEVINL void async16(const void* g, void* l) {
  __builtin_amdgcn_global_load_lds((as1c_u32p)g, (as3_u32p)l, 16, 0, 0);
}

__global__ __launch_bounds__(256) void k_gemm(const unsigned short* __restrict__ X,
                                              const unsigned short* __restrict__ W,
                                              const float* __restrict__ bias,
                                              unsigned short* __restrict__ XWr) {
  __shared__ unsigned short Asm[8192];
  __shared__ unsigned short Bsm[8192];
  const int nt = blockIdx.x, mt = blockIdx.y;
  const int tid = threadIdx.x, lane = tid & 63, w = tid >> 6;
  const int wm = w & 1, wn = w >> 1;
  const int ul = lane & 15, q = lane >> 4;
  const int srow = lane >> 3, schunk = lane & 7;

  f32x4 acc[4][4];
  const f32x4 fz = {0.f, 0.f, 0.f, 0.f};
#pragma unroll
  for (int i = 0; i < 4; i++)
#pragma unroll
    for (int j = 0; j < 4; j++) acc[i][j] = fz;

  for (int k0 = 0; k0 < 512; k0 += 64) {
    __syncthreads();
#pragma unroll
    for (int rep = 0; rep < 4; rep++) {
      const int row = rep * 32 + w * 8 + srow;
      const int ca = (schunk ^ (row & 7)) << 3;
      async16(X + (size_t)(mt * 128 + row) * 512 + k0 + ca, Asm + (rep * 32 + w * 8) * 64);
      async16(W + (size_t)(nt * 128 + row) * 512 + k0 + ca, Bsm + (rep * 32 + w * 8) * 64);
    }
    __syncthreads();
#pragma unroll
    for (int kk = 0; kk < 2; kk++) {
      bf16x8 af[4], bfr[4];
#pragma unroll
      for (int i = 0; i < 4; i++) {
        const int ra = wm * 64 + i * 16 + ul;
        const int pa = (kk * 4 + q) ^ (ra & 7);
        af[i] = *(const bf16x8*)(Asm + ra * 64 + pa * 8);
        const int rb = wn * 64 + i * 16 + ul;
        const int pb = (kk * 4 + q) ^ (rb & 7);
        bfr[i] = *(const bf16x8*)(Bsm + rb * 64 + pb * 8);
      }
#pragma unroll
      for (int i = 0; i < 4; i++)
#pragma unroll
        for (int j = 0; j < 4; j++)
          acc[i][j] = __builtin_amdgcn_mfma_f32_16x16x32_bf16(af[i], bfr[j], acc[i][j], 0, 0, 0);
    }
  }

  const int s = mt * 2 + wm;
  const int nb = nt * 128 + wn * 64;
#pragma unroll
  for (int j = 0; j < 4; j++) {
    const int n = nb + j * 16;
    const int dir = n >> 11, g = (n >> 9) & 3, slot = (n >> 4) & 31;
    const float bs = bias[n + ul];
#pragma unroll
    for (int i = 0; i < 4; i++) {
      const f32x4 v = acc[i][j];
      uint2 o;
      o.x = (unsigned)f2bf(v[0] + bs) | ((unsigned)f2bf(v[1] + bs) << 16);
      o.y = (unsigned)f2bf(v[2] + bs) | ((unsigned)f2bf(v[3] + bs) << 16);
      const size_t idx = ((((((size_t)s * 2 + dir) * 32 + slot) * 4 + g) * 4 + i) * 64 + lane) * 4;
      *(uint2*)(XWr + idx) = o;
    }
  }
}

// ---------------------------------------------------------------------------
// 5) persistent bidirectional LSTM. 64 blocks x 256 threads.
//    block (dir,slot) owns units [slot*16,+16); wave wv owns batch rows
//    [wv*16,+16). Per-WAVE barrier: h write-through -> vmcnt(0) drain -> own
//    tag store -> poll peer tags. Step-body order tuned for vmcnt FIFO:
//    h loads, then next-step XWr prefetch (hidden behind MFMA), then MFMA,
//    gates, hs+hg stores sharing one drain, tag, poll.
// ---------------------------------------------------------------------------
__global__ __launch_bounds__(256, 1) void k_lstm(const unsigned short* __restrict__ Whh,
                                                 const unsigned short* __restrict__ XWr,
                                                 const float* __restrict__ c0,
                                                 unsigned short* __restrict__ hg,
                                                 unsigned short* __restrict__ hs,
                                                 unsigned int* __restrict__ tags) {
  __shared__ uint4 wlds[4096];                             // 64 KB W_hh slice
  __shared__ __align__(16) unsigned short hstage[4][320];  // per-wave [16 rows][20] padded
  const int tid = threadIdx.x, lane = tid & 63, wv = tid >> 6;
  const int dir = blockIdx.x >> 5, slot = blockIdx.x & 31;
  const int u0 = slot << 4;
  const int ul = lane & 15, q = lane >> 4;
  const int b_base = wv << 4;
  const int rlocal = lane >> 2, chunk = lane & 3;

  // stage W_hh slice: frag f=kk*4+g; lane: row g*512+u0+ul, k-chunk kk*32+q*8
#pragma unroll
  for (int i = 0; i < 16; i++) {
    const int f = i * 4 + wv;
    const int g = f & 3, kk = f >> 2;
    const int row = dir * 2048 + g * 512 + u0 + ul;
    wlds[f * 64 + lane] = *(const uint4*)(Whh + (size_t)row * 512 + kk * 32 + q * 8);
  }

  float c[4];
#pragma unroll
  for (int r = 0; r < 4; r++)
    c[r] = c0[((size_t)dir * 64 + b_base + q * 4 + r) * 512 + u0 + ul];

  // tag lines: [dir][wv][slot], 128-B stride (32 uints)
  unsigned int* mytag = tags + (((size_t)dir * 4 + wv) * 32 + slot) * 32;
  const unsigned int* ptag = tags + ((size_t)dir * 4 + wv) * 32 * 32;

  // prefetch XWr fragments for step 0
  uint2 xg[4];
  {
    const int tt0 = dir ? 511 : 0;
#pragma unroll
    for (int g = 0; g < 4; g++)
      xg[g] = *(const uint2*)(XWr + (size_t)tt0 * 262144 +
                              (((((size_t)dir * 32 + slot) * 4 + g) * 4 + wv) * 64 + lane) * 4);
  }

  __syncthreads();   // wlds ready (only barrier in the kernel)

  for (int t = 0; t < 512; t++) {
    const int tt = dir ? (511 - t) : t;
    const size_t rbase = ((size_t)(t & 1) * 2 + dir) * 32768;   // read buf (shorts)

    // --- load h_{t-1}: A-frag rows b_base+ul, 8 units per (kk,q) ---
    unsigned long long ha[32];
#pragma unroll
    for (int kk = 0; kk < 16; kk++) {
      const int slotS = 2 * kk + (q >> 1);
      const unsigned long long* p = (const unsigned long long*)
          (hg + rbase + ((size_t)slotS * 64 + b_base + ul) * 16 + (q & 1) * 8);
      ha[2 * kk]     = __hip_atomic_load(p,     __ATOMIC_RELAXED, __HIP_MEMORY_SCOPE_AGENT);
      ha[2 * kk + 1] = __hip_atomic_load(p + 1, __ATOMIC_RELAXED, __HIP_MEMORY_SCOPE_AGENT);
    }

    // --- next-step XWr prefetch: issued ~2000 cy before the poll that would
    //     otherwise FIFO-wait on it; hidden behind h-load wait + MFMA ---
    uint2 xgn[4];
    if (t < 511) {
      const int ttn = dir ? (511 - (t + 1)) : (t + 1);
#pragma unroll
      for (int g = 0; g < 4; g++)
        xgn[g] = *(const uint2*)(XWr + (size_t)ttn * 262144 +
                                 (((((size_t)dir * 32 + slot) * 4 + g) * 4 + wv) * 64 + lane) * 4);
    }

    f32x4 acc[4];
    const f32x4 fz = {0.f, 0.f, 0.f, 0.f};
    acc[0] = fz; acc[1] = fz; acc[2] = fz; acc[3] = fz;
#pragma unroll
    for (int kk = 0; kk < 16; kk++) {
      uint4 av;
      av.x = (unsigned)ha[2 * kk];
      av.y = (unsigned)(ha[2 * kk] >> 32);
      av.z = (unsigned)ha[2 * kk + 1];
      av.w = (unsigned)(ha[2 * kk + 1] >> 32);
      const bf16x8 a8 = as_bf16x8(av);
#pragma unroll
      for (int g = 0; g < 4; g++) {
        const bf16x8 b8 = as_bf16x8(wlds[(kk * 4 + g) * 64 + lane]);
        acc[g] = __builtin_amdgcn_mfma_f32_16x16x32_bf16(a8, b8, acc[g], 0, 0, 0);
      }
    }

    // --- gates + state update; stage h into wave-private padded LDS ---
#pragma unroll
    for (int r = 0; r < 4; r++) {
      const float gi = acc[0][r] + selbf(xg[0], r);
      const float gf = acc[1][r] + selbf(xg[1], r);
      const float gg = acc[2][r] + selbf(xg[2], r);
      const float go = acc[3][r] + selbf(xg[3], r);
      const float i_ = fsigmoid(gi);
      const float f_ = fsigmoid(gf);
      const float g_ = ftanh(gg);
      const float o_ = fsigmoid(go);
      c[r] = f_ * c[r] + i_ * g_;
      const float h = o_ * ftanh(c[r]);
      hstage[wv][(q * 4 + r) * 20 + ul] = f2bf(h);   // conflict-free (pad 20)
    }

    // compiler memory barrier: hstage u16 stores MUST precede the packed read
    asm volatile("" ::: "memory");

    // pack: this wave's row rlocal, units chunk*4..+4 (8 B, aligned)
    unsigned long long v;
    __builtin_memcpy(&v, &hstage[wv][rlocal * 20 + chunk * 4], 8);

    // hs history store first (plain L2 store; completes in the drain's shadow)
    *(unsigned long long*)(hs + ((size_t)tt * 64 + b_base + rlocal) * 1024 +
                           dir * 512 + u0 + chunk * 4) = v;

    if (t < 511) {
      // write-through h_t to the other buffer (block-contiguous region)
      const size_t wbase = ((size_t)((t & 1) ^ 1) * 2 + dir) * 32768;
      __hip_atomic_store(
          (unsigned long long*)(hg + wbase + ((size_t)slot * 64 + b_base + rlocal) * 16 + chunk * 4),
          v, __ATOMIC_RELAXED, __HIP_MEMORY_SCOPE_AGENT);
      asm volatile("s_waitcnt vmcnt(0)" ::: "memory");    // drain hs+hg (LLC RT)
      if (lane == 0)
        __hip_atomic_store(mytag, (unsigned)(t + 1), __ATOMIC_RELAXED,
                           __HIP_MEMORY_SCOPE_AGENT);

      // poll the 32 tags of this row-group (only tag traffic outstanding now)
      const unsigned target = (unsigned)(t + 1);
      int spins = 0;
      for (;;) {
        unsigned tg = 0xFFFFFFFFu;
        if (lane < 32)
          tg = __hip_atomic_load(ptag + (size_t)lane * 32, __ATOMIC_RELAXED,
                                 __HIP_MEMORY_SCOPE_AGENT);
        if (__all(tg >= target)) break;
        if (++spins > 3000000) break;   // hang guard
      }
      xg[0] = xgn[0]; xg[1] = xgn[1]; xg[2] = xgn[2]; xg[3] = xgn[3];
    }
  }
}

// ---------------------------------------------------------------------------
// 6) emissions
// ---------------------------------------------------------------------------
DEVINL void unpack8(uint4 v, float* o) {
  o[0] = bf2f(v.x); o[1] = bf2f(v.x >> 16);
  o[2] = bf2f(v.y); o[3] = bf2f(v.y >> 16);
  o[4] = bf2f(v.z); o[5] = bf2f(v.z >> 16);
  o[6] = bf2f(v.w); o[7] = bf2f(v.w >> 16);
}

__global__ __launch_bounds__(256) void k_emis(const unsigned short* __restrict__ hs,
                                              const float* __restrict__ wlin,
                                              const float* __restrict__ blin,
                                              float* __restrict__ em) {
  const int lane = threadIdx.x & 63, wv = threadIdx.x >> 6;
  const int p = blockIdx.x * 4 + wv;   // s*64+b
  const int s = p >> 6, b = p & 63;
  const uint4* row = (const uint4*)(hs + (size_t)p * 1024);
  const uint4 v0 = row[lane * 2], v1 = row[lane * 2 + 1];
  float hv[16];
  unpack8(v0, hv);
  unpack8(v1, hv + 8);
#pragma unroll 1
  for (int tag = 0; tag < 9; tag++) {
    const float4* wr = (const float4*)(wlin + (size_t)tag * 1024 + lane * 16);
    float sum = 0.f;
#pragma unroll
    for (int jj = 0; jj < 4; jj++) {
      const float4 w4 = wr[jj];
      sum += hv[jj * 4 + 0] * w4.x + hv[jj * 4 + 1] * w4.y +
             hv[jj * 4 + 2] * w4.z + hv[jj * 4 + 3] * w4.w;
    }
#pragma unroll
    for (int off = 32; off > 0; off >>= 1) sum += __shfl_down(sum, off);
    if (lane == 0) em[((size_t)b * 512 + s) * 9 + tag] = sum + blin[tag];
  }
}

// ---------------------------------------------------------------------------
// 7) CRF
// ---------------------------------------------------------------------------
__global__ void k_crf(const float* __restrict__ em, const int* __restrict__ tags,
                      const float* __restrict__ st, const float* __restrict__ et,
                      const float* __restrict__ tr, float* __restrict__ loss) {
  const int b = blockIdx.x, lane = threadIdx.x;
  const float L2E = 1.4426950408889634f, LN2 = 0.6931471805599453f;

  float np = 0.f;
  for (int s = lane; s < 512; s += 64) {
    const int tg = tags[b * 512 + s];
    np += em[((size_t)b * 512 + s) * 9 + tg];
    if (s > 0) np += tr[tags[b * 512 + s - 1] * 9 + tg];
  }
#pragma unroll
  for (int off = 32; off > 0; off >>= 1) np += __shfl_down(np, off);

  const int j = (lane < 9) ? lane : 0;
  float tcol[9];
#pragma unroll
  for (int i = 0; i < 9; i++) tcol[i] = tr[i * 9 + j];
  float alpha = st[j] + em[((size_t)b * 512 + 0) * 9 + j];
  for (int s = 1; s < 512; s++) {
    float abc[9];
#pragma unroll
    for (int i = 0; i < 9; i++) abc[i] = __shfl(alpha, i) + tcol[i];
    float mx = abc[0];
#pragma unroll
    for (int i = 1; i < 9; i++) mx = fmaxf(mx, abc[i]);
    float sm = 0.f;
#pragma unroll
    for (int i = 0; i < 9; i++) sm += exp2f((abc[i] - mx) * L2E);
    alpha = mx + log2f(sm) * LN2 + em[((size_t)b * 512 + s) * 9 + j];
  }
  float v = (lane < 9) ? (alpha + et[j]) : -3.0e38f;
  float mx = v;
#pragma unroll
  for (int off = 32; off > 0; off >>= 1) mx = fmaxf(mx, __shfl_xor(mx, off));
  float se = (lane < 9) ? exp2f((v - mx) * L2E) : 0.f;
#pragma unroll
  for (int off = 32; off > 0; off >>= 1) se += __shfl_xor(se, off);
  const float denom = mx + log2f(se) * LN2;

  if (lane == 0) {
    const float num = np + st[tags[b * 512]] + et[tags[b * 512 + 511]];
    atomicAdd(loss, num - denom);
  }
}

__global__ void k_final(const float* __restrict__ loss, float* __restrict__ out) {
  out[0] = -loss[0] * (1.f / 64.f);
}

// ---------------------------------------------------------------------------
extern "C" void kernel_launch(void* const* d_in, const int* in_sizes, int n_in,
                              void* d_out, int out_size, void* d_ws, size_t ws_size,
                              hipStream_t stream) {
  (void)in_sizes; (void)n_in; (void)out_size; (void)ws_size;
  const int*   sentence = (const int*)d_in[0];
  const int*   tags     = (const int*)d_in[1];
  const float* emb      = (const float*)d_in[2];
  const float* w_ih_f   = (const float*)d_in[3];
  const float* w_hh_f   = (const float*)d_in[4];
  const float* b_ih_f   = (const float*)d_in[5];
  const float* b_hh_f   = (const float*)d_in[6];
  const float* w_ih_b   = (const float*)d_in[7];
  const float* w_hh_b   = (const float*)d_in[8];
  const float* b_ih_b   = (const float*)d_in[9];
  const float* b_hh_b   = (const float*)d_in[10];
  const float* w_lin    = (const float*)d_in[11];
  const float* b_lin    = (const float*)d_in[12];
  const float* start_t  = (const float*)d_in[13];
  const float* end_t    = (const float*)d_in[14];
  const float* trans    = (const float*)d_in[15];
  const float* h0       = (const float*)d_in[16];
  const float* c0       = (const float*)d_in[17];

  char* ws = (char*)d_ws;
  unsigned short* XWr = (unsigned short*)(ws + XWR_OFF);
  unsigned short* X   = (unsigned short*)(ws + X_OFF);
  unsigned short* HS  = (unsigned short*)(ws + HS_OFF);
  unsigned short* WIH = (unsigned short*)(ws + WIH_OFF);
  unsigned short* WHH = (unsigned short*)(ws + WHH_OFF);
  float*          BIAS= (float*)(ws + BIAS_OFF);
  unsigned short* HG  = (unsigned short*)(ws + H_OFF);
  float*          EM  = (float*)(ws + EM_OFF);
  // X region is dead after k_gemm -> reuse its head for tags (32 KB) + loss
  unsigned int*   TAGS= (unsigned int*)(ws + X_OFF);
  float*          LOSS= (float*)(ws + X_OFF + 32768);

  k_gather<<<32768, 128, 0, stream>>>(sentence, emb, X);
  k_prep<<<4096, 128, 0, stream>>>(w_ih_f, w_hh_f, b_ih_f, b_hh_f,
                                   w_ih_b, w_hh_b, b_ih_b, b_hh_b, WIH, WHH, BIAS);
  k_inith<<<64, 256, 0, stream>>>(h0, HG);
  k_gemm<<<dim3(32, 256), 256, 0, stream>>>(X, WIH, BIAS, XWr);
  hipMemsetAsync(TAGS, 0, 32768 + 64, stream);   // tags + loss, after X is consumed
  k_lstm<<<64, 256, 0, stream>>>(WHH, XWr, c0, HG, HS, TAGS);
  k_emis<<<8192, 256, 0, stream>>>(HS, w_lin, b_lin, EM);
  k_crf<<<64, 64, 0, stream>>>(EM, tags, start_t, end_t, trans, LOSS);
  k_final<<<1, 1, 0, stream>>>(LOSS, (float*)d_out);
}

// Round 6
// 2461.556 us; speedup vs baseline: 1.1538x; 1.1538x over previous
//
#include <hip/hip_runtime.h>
#include <hip/hip_bf16.h>
#include <cstdint>
#include <cstddef>

// ---------------------------------------------------------------------------
// BiLSTM-CRF forward on MI355X.
// gather(emb) -> cast weights -> MFMA GEMM (x@Wih^T+bias, fragment order) ->
// persistent 512-step LSTM -> emissions -> CRF -> loss.
// r6: LSTM step protocol replaced by pure DATAFLOW. h buffers are mod-4 and
// canary-initialized (0x7F7F bf16 = 3.39e38, unreachable since |h|<1);
// producers fire-and-forget write-through 8-B stores (atomic -> a chunk is
// all-canary or all-data); consumers poll the data itself until canary-free
// and then use the loaded registers directly. No tags, no vmcnt(0) drain,
// no per-step barrier: detect+load fuse into ~1 LLC round trip.
// Deferred reset: at step t each wave re-canaries its own production region
// in buf[(t-1)&3] (safe: validating step-t data from all slots proves all
// step-(t-1) readers of that region finished; same-wave store FIFO orders
// the reset before the buffer's rewrite at t+2).
// ---------------------------------------------------------------------------

typedef __attribute__((ext_vector_type(4))) float f32x4;
typedef __attribute__((ext_vector_type(8))) short bf16x8;

#define DEVINL __device__ __forceinline__

// ---- workspace layout (bytes) ----
static constexpr size_t XWR_OFF  = 0;            // 268,435,456  (S,dir,slot,g,wv,lane,reg) bf16
static constexpr size_t X_OFF    = 268435456;    //  33,554,432  x bf16 (reused after gemm: loss + hg4)
static constexpr size_t HS_OFF   = 301989888;    //  67,108,864  hs bf16 (512 x 64 x 1024)
static constexpr size_t WIH_OFF  = 369098752;    //   4,194,304  Wih cat bf16 (4096 x 512)
static constexpr size_t WHH_OFF  = 373293056;    //   4,194,304  Whh cat bf16 (4096 x 512)
static constexpr size_t BIAS_OFF = 377487360;    //      16,384  bias f32 (4096)
static constexpr size_t EM_OFF   = 377765888;    //   1,179,648  em f32 [64][512][9]
// hg4 (4 x 128 KB) + loss live in the dead X region after k_gemm.

DEVINL unsigned short f2bf(float f) {
  unsigned u = __builtin_bit_cast(unsigned, f);
  unsigned r = u + 0x7fffu + ((u >> 16) & 1u);
  return (unsigned short)(r >> 16);
}
DEVINL float bf2f(unsigned int h) {
  unsigned u = (h & 0xffffu) << 16;
  return __builtin_bit_cast(float, u);
}
DEVINL bf16x8 as_bf16x8(uint4 v) { return __builtin_bit_cast(bf16x8, v); }

DEVINL float fsigmoid(float x) {
  const float e = exp2f(-1.4426950408889634f * x);
  return __builtin_amdgcn_rcpf(1.f + e);
}
DEVINL float ftanh(float x) {
  const float e = exp2f(2.8853900817779268f * x);
  return 1.f - 2.f * __builtin_amdgcn_rcpf(e + 1.f);
}
DEVINL float selbf(uint2 v, int r) {
  const unsigned u = (r < 2) ? v.x : v.y;
  return bf2f((r & 1) ? (u >> 16) : u);
}

// ---------------------------------------------------------------------------
// 1) embedding gather
// ---------------------------------------------------------------------------
__global__ void k_gather(const int* __restrict__ sent, const float* __restrict__ emb,
                         unsigned short* __restrict__ x) {
  const int m = blockIdx.x;            // 0..32767 = s*64+b
  const int s = m >> 6, b = m & 63;
  const int tok = sent[b * 512 + s];
  const float4 v = ((const float4*)(emb + (size_t)tok * 512))[threadIdx.x];
  uint2 o;
  o.x = (unsigned)f2bf(v.x) | ((unsigned)f2bf(v.y) << 16);
  o.y = (unsigned)f2bf(v.z) | ((unsigned)f2bf(v.w) << 16);
  ((uint2*)(x + (size_t)m * 512))[threadIdx.x] = o;
}

// ---------------------------------------------------------------------------
// 2) weight cast/concat
// ---------------------------------------------------------------------------
__global__ void k_prep(const float* __restrict__ wihf, const float* __restrict__ whhf,
                       const float* __restrict__ bihf, const float* __restrict__ bhhf,
                       const float* __restrict__ wihb, const float* __restrict__ whhb,
                       const float* __restrict__ bihb, const float* __restrict__ bhhb,
                       unsigned short* __restrict__ Wih, unsigned short* __restrict__ Whh,
                       float* __restrict__ bias) {
  const int n = blockIdx.x;
  const int dir = n >> 11, r = n & 2047;
  const float* wi = dir ? wihb : wihf;
  const float* wh = dir ? whhb : whhf;
  const float4 a = ((const float4*)(wi + (size_t)r * 512))[threadIdx.x];
  const float4 c = ((const float4*)(wh + (size_t)r * 512))[threadIdx.x];
  uint2 oa, oc;
  oa.x = (unsigned)f2bf(a.x) | ((unsigned)f2bf(a.y) << 16);
  oa.y = (unsigned)f2bf(a.z) | ((unsigned)f2bf(a.w) << 16);
  oc.x = (unsigned)f2bf(c.x) | ((unsigned)f2bf(c.y) << 16);
  oc.y = (unsigned)f2bf(c.z) | ((unsigned)f2bf(c.w) << 16);
  ((uint2*)(Wih + (size_t)n * 512))[threadIdx.x] = oa;
  ((uint2*)(Whh + (size_t)n * 512))[threadIdx.x] = oc;
  if (threadIdx.x == 0)
    bias[n] = dir ? (bihb[r] + bhhb[r]) : (bihf[r] + bhhf[r]);
}

// ---------------------------------------------------------------------------
// 3) h buffers: buf0 = bf16(h0), buf1..3 = canary. Layout per buffer:
//    [dir][slot][row][16u], buffer stride 65536 shorts. Write-through u64.
// ---------------------------------------------------------------------------
__global__ void k_inith(const float* __restrict__ h0, unsigned short* __restrict__ hg) {
  const int gi = blockIdx.x * 256 + threadIdx.x;   // 16384 chunks of 4 units
  const int dir = gi >> 13, rem = gi & 8191;
  const int row = rem >> 7, c = rem & 127;
  const int slot = c >> 2, off = (c & 3) * 4;
  const float4 v = *(const float4*)(h0 + ((size_t)(dir * 64 + row)) * 512 + slot * 16 + off);
  const unsigned long long p =
      (unsigned long long)f2bf(v.x) | ((unsigned long long)f2bf(v.y) << 16) |
      ((unsigned long long)f2bf(v.z) << 32) | ((unsigned long long)f2bf(v.w) << 48);
  const size_t base = (((size_t)dir * 32 + slot) * 64 + row) * 16 + off;
  __hip_atomic_store((unsigned long long*)(hg + base), p,
                     __ATOMIC_RELAXED, __HIP_MEMORY_SCOPE_AGENT);
  const unsigned long long CAN = 0x7F7F7F7F7F7F7F7FULL;
#pragma unroll
  for (int b = 1; b < 4; b++)
    __hip_atomic_store((unsigned long long*)(hg + (size_t)b * 65536 + base), CAN,
                       __ATOMIC_RELAXED, __HIP_MEMORY_SCOPE_AGENT);
}

// ---------------------------------------------------------------------------
// 4) GEMM: M=32768 N=4096 K=512, 128x128 tiles, global_load_lds(16B),
//    XOR-swizzled LDS. Output bf16 in MFMA-fragment order.
// ---------------------------------------------------------------------------
typedef __attribute__((address_space(1))) const unsigned int* as1c_u32p;
typedef __attribute__((address_space(3))) unsigned int* as3_u32p;

DEVINL void async16(const void* g, void* l) {
  __builtin_amdgcn_global_load_lds((as1c_u32p)g, (as3_u32p)l, 16, 0, 0);
}

__global__ __launch_bounds__(256) void k_gemm(const unsigned short* __restrict__ X,
                                              const unsigned short* __restrict__ W,
                                              const float* __restrict__ bias,
                                              unsigned short* __restrict__ XWr) {
  __shared__ unsigned short Asm[8192];
  __shared__ unsigned short Bsm[8192];
  const int nt = blockIdx.x, mt = blockIdx.y;
  const int tid = threadIdx.x, lane = tid & 63, w = tid >> 6;
  const int wm = w & 1, wn = w >> 1;
  const int ul = lane & 15, q = lane >> 4;
  const int srow = lane >> 3, schunk = lane & 7;

  f32x4 acc[4][4];
  const f32x4 fz = {0.f, 0.f, 0.f, 0.f};
#pragma unroll
  for (int i = 0; i < 4; i++)
#pragma unroll
    for (int j = 0; j < 4; j++) acc[i][j] = fz;

  for (int k0 = 0; k0 < 512; k0 += 64) {
    __syncthreads();
#pragma unroll
    for (int rep = 0; rep < 4; rep++) {
      const int row = rep * 32 + w * 8 + srow;
      const int ca = (schunk ^ (row & 7)) << 3;
      async16(X + (size_t)(mt * 128 + row) * 512 + k0 + ca, Asm + (rep * 32 + w * 8) * 64);
      async16(W + (size_t)(nt * 128 + row) * 512 + k0 + ca, Bsm + (rep * 32 + w * 8) * 64);
    }
    __syncthreads();
#pragma unroll
    for (int kk = 0; kk < 2; kk++) {
      bf16x8 af[4], bfr[4];
#pragma unroll
      for (int i = 0; i < 4; i++) {
        const int ra = wm * 64 + i * 16 + ul;
        const int pa = (kk * 4 + q) ^ (ra & 7);
        af[i] = *(const bf16x8*)(Asm + ra * 64 + pa * 8);
        const int rb = wn * 64 + i * 16 + ul;
        const int pb = (kk * 4 + q) ^ (rb & 7);
        bfr[i] = *(const bf16x8*)(Bsm + rb * 64 + pb * 8);
      }
#pragma unroll
      for (int i = 0; i < 4; i++)
#pragma unroll
        for (int j = 0; j < 4; j++)
          acc[i][j] = __builtin_amdgcn_mfma_f32_16x16x32_bf16(af[i], bfr[j], acc[i][j], 0, 0, 0);
    }
  }

  const int s = mt * 2 + wm;
  const int nb = nt * 128 + wn * 64;
#pragma unroll
  for (int j = 0; j < 4; j++) {
    const int n = nb + j * 16;
    const int dir = n >> 11, g = (n >> 9) & 3, slot = (n >> 4) & 31;
    const float bs = bias[n + ul];
#pragma unroll
    for (int i = 0; i < 4; i++) {
      const f32x4 v = acc[i][j];
      uint2 o;
      o.x = (unsigned)f2bf(v[0] + bs) | ((unsigned)f2bf(v[1] + bs) << 16);
      o.y = (unsigned)f2bf(v[2] + bs) | ((unsigned)f2bf(v[3] + bs) << 16);
      const size_t idx = ((((((size_t)s * 2 + dir) * 32 + slot) * 4 + g) * 4 + i) * 64 + lane) * 4;
      *(uint2*)(XWr + idx) = o;
    }
  }
}

// ---------------------------------------------------------------------------
// 5) persistent bidirectional LSTM, dataflow version. 64 blocks x 256 thr.
//    block (dir,slot) owns units [slot*16,+16); wave wv owns batch rows
//    [wv*16,+16). Consumers poll h data directly (canary = not-yet-written);
//    producers fire-and-forget write-through stores. Mod-4 buffers with
//    deferred canary reset.
// ---------------------------------------------------------------------------
__global__ __launch_bounds__(256, 1) void k_lstm(const unsigned short* __restrict__ Whh,
                                                 const unsigned short* __restrict__ XWr,
                                                 const float* __restrict__ c0,
                                                 unsigned short* __restrict__ hg,
                                                 unsigned short* __restrict__ hs) {
  __shared__ uint4 wlds[4096];                             // 64 KB W_hh slice
  __shared__ __align__(16) unsigned short hstage[4][320];  // per-wave padded
  const int tid = threadIdx.x, lane = tid & 63, wv = tid >> 6;
  const int dir = blockIdx.x >> 5, slot = blockIdx.x & 31;
  const int u0 = slot << 4;
  const int ul = lane & 15, q = lane >> 4;
  const int b_base = wv << 4;
  const int rlocal = lane >> 2, chunk = lane & 3;
  const unsigned long long CAN = 0x7F7F7F7F7F7F7F7FULL;

  // stage W_hh slice: frag f=kk*4+g; lane: row g*512+u0+ul, k-chunk kk*32+q*8
#pragma unroll
  for (int i = 0; i < 16; i++) {
    const int f = i * 4 + wv;
    const int g = f & 3, kk = f >> 2;
    const int row = dir * 2048 + g * 512 + u0 + ul;
    wlds[f * 64 + lane] = *(const uint4*)(Whh + (size_t)row * 512 + kk * 32 + q * 8);
  }

  float c[4];
#pragma unroll
  for (int r = 0; r < 4; r++)
    c[r] = c0[((size_t)dir * 64 + b_base + q * 4 + r) * 512 + u0 + ul];

  // prefetch XWr fragments for step 0
  uint2 xg[4];
  {
    const int tt0 = dir ? 511 : 0;
#pragma unroll
    for (int g = 0; g < 4; g++)
      xg[g] = *(const uint2*)(XWr + (size_t)tt0 * 262144 +
                              (((((size_t)dir * 32 + slot) * 4 + g) * 4 + wv) * 64 + lane) * 4);
  }

  __syncthreads();   // wlds ready (only barrier in the kernel)

  for (int t = 0; t < 512; t++) {
    const int tt = dir ? (511 - t) : t;
    const size_t rbase = ((size_t)(t & 3) * 2 + dir) * 32768;   // read buf (shorts)

    // --- fused poll + load: read h fragments until canary-free ---
    unsigned long long ha[32];
    int rounds = 0;
    for (;;) {
      unsigned bad = 0;
#pragma unroll
      for (int kk = 0; kk < 16; kk++) {
        const int slotS = 2 * kk + (q >> 1);
        const unsigned long long* p = (const unsigned long long*)
            (hg + rbase + ((size_t)slotS * 64 + b_base + ul) * 16 + (q & 1) * 8);
        ha[2 * kk]     = __hip_atomic_load(p,     __ATOMIC_RELAXED, __HIP_MEMORY_SCOPE_AGENT);
        ha[2 * kk + 1] = __hip_atomic_load(p + 1, __ATOMIC_RELAXED, __HIP_MEMORY_SCOPE_AGENT);
      }
#pragma unroll
      for (int i = 0; i < 32; i++)
        bad |= (((unsigned)ha[i] & 0xFFFFu) == 0x7F7Fu) ? 1u : 0u;
      if (__all(bad == 0)) break;
      if (++rounds > 2000000) break;   // hang guard
      __builtin_amdgcn_s_sleep(1);
    }

    // --- deferred reset: re-canary own production region in buf[(t-1)&3] ---
    if (t >= 1) {
      __hip_atomic_store(
          (unsigned long long*)(hg + ((size_t)((t - 1) & 3) * 2 + dir) * 32768 +
                                ((size_t)slot * 64 + b_base + rlocal) * 16 + chunk * 4),
          CAN, __ATOMIC_RELAXED, __HIP_MEMORY_SCOPE_AGENT);
    }

    // --- MFMA: gates += h_{t-1} @ Whh^T ---
    f32x4 acc[4];
    const f32x4 fz = {0.f, 0.f, 0.f, 0.f};
    acc[0] = fz; acc[1] = fz; acc[2] = fz; acc[3] = fz;
#pragma unroll
    for (int kk = 0; kk < 16; kk++) {
      uint4 av;
      av.x = (unsigned)ha[2 * kk];
      av.y = (unsigned)(ha[2 * kk] >> 32);
      av.z = (unsigned)ha[2 * kk + 1];
      av.w = (unsigned)(ha[2 * kk + 1] >> 32);
      const bf16x8 a8 = as_bf16x8(av);
#pragma unroll
      for (int g = 0; g < 4; g++) {
        const bf16x8 b8 = as_bf16x8(wlds[(kk * 4 + g) * 64 + lane]);
        acc[g] = __builtin_amdgcn_mfma_f32_16x16x32_bf16(a8, b8, acc[g], 0, 0, 0);
      }
    }

    // --- gates + state update; stage h into wave-private padded LDS ---
#pragma unroll
    for (int r = 0; r < 4; r++) {
      const float gi = acc[0][r] + selbf(xg[0], r);
      const float gf = acc[1][r] + selbf(xg[1], r);
      const float gg = acc[2][r] + selbf(xg[2], r);
      const float go = acc[3][r] + selbf(xg[3], r);
      const float i_ = fsigmoid(gi);
      const float f_ = fsigmoid(gf);
      const float g_ = ftanh(gg);
      const float o_ = fsigmoid(go);
      c[r] = f_ * c[r] + i_ * g_;
      const float h = o_ * ftanh(c[r]);
      hstage[wv][(q * 4 + r) * 20 + ul] = f2bf(h);   // conflict-free (pad 20)
    }

    // compiler memory barrier: hstage u16 stores MUST precede the packed read
    asm volatile("" ::: "memory");

    // pack: this wave's row rlocal, units chunk*4..+4 (8 B, aligned)
    unsigned long long v;
    __builtin_memcpy(&v, &hstage[wv][rlocal * 20 + chunk * 4], 8);

    // --- fire-and-forget stores: h_t (write-through), hs history (cached) ---
    if (t < 511) {
      const size_t wbase = ((size_t)((t + 1) & 3) * 2 + dir) * 32768;
      __hip_atomic_store(
          (unsigned long long*)(hg + wbase + ((size_t)slot * 64 + b_base + rlocal) * 16 + chunk * 4),
          v, __ATOMIC_RELAXED, __HIP_MEMORY_SCOPE_AGENT);
    }
    *(unsigned long long*)(hs + ((size_t)tt * 64 + b_base + rlocal) * 1024 +
                           dir * 512 + u0 + chunk * 4) = v;

    // --- XWr prefetch for t+1 (hides under next step's poll window) ---
    if (t < 511) {
      const int ttn = dir ? (511 - (t + 1)) : (t + 1);
#pragma unroll
      for (int g = 0; g < 4; g++)
        xg[g] = *(const uint2*)(XWr + (size_t)ttn * 262144 +
                                (((((size_t)dir * 32 + slot) * 4 + g) * 4 + wv) * 64 + lane) * 4);
    }
  }
}

// ---------------------------------------------------------------------------
// 6) emissions
// ---------------------------------------------------------------------------
DEVINL void unpack8(uint4 v, float* o) {
  o[0] = bf2f(v.x); o[1] = bf2f(v.x >> 16);
  o[2] = bf2f(v.y); o[3] = bf2f(v.y >> 16);
  o[4] = bf2f(v.z); o[5] = bf2f(v.z >> 16);
  o[6] = bf2f(v.w); o[7] = bf2f(v.w >> 16);
}

__global__ __launch_bounds__(256) void k_emis(const unsigned short* __restrict__ hs,
                                              const float* __restrict__ wlin,
                                              const float* __restrict__ blin,
                                              float* __restrict__ em) {
  const int lane = threadIdx.x & 63, wv = threadIdx.x >> 6;
  const int p = blockIdx.x * 4 + wv;   // s*64+b
  const int s = p >> 6, b = p & 63;
  const uint4* row = (const uint4*)(hs + (size_t)p * 1024);
  const uint4 v0 = row[lane * 2], v1 = row[lane * 2 + 1];
  float hv[16];
  unpack8(v0, hv);
  unpack8(v1, hv + 8);
#pragma unroll 1
  for (int tag = 0; tag < 9; tag++) {
    const float4* wr = (const float4*)(wlin + (size_t)tag * 1024 + lane * 16);
    float sum = 0.f;
#pragma unroll
    for (int jj = 0; jj < 4; jj++) {
      const float4 w4 = wr[jj];
      sum += hv[jj * 4 + 0] * w4.x + hv[jj * 4 + 1] * w4.y +
             hv[jj * 4 + 2] * w4.z + hv[jj * 4 + 3] * w4.w;
    }
#pragma unroll
    for (int off = 32; off > 0; off >>= 1) sum += __shfl_down(sum, off);
    if (lane == 0) em[((size_t)b * 512 + s) * 9 + tag] = sum + blin[tag];
  }
}

// ---------------------------------------------------------------------------
// 7) CRF
// ---------------------------------------------------------------------------
__global__ void k_crf(const float* __restrict__ em, const int* __restrict__ tags,
                      const float* __restrict__ st, const float* __restrict__ et,
                      const float* __restrict__ tr, float* __restrict__ loss) {
  const int b = blockIdx.x, lane = threadIdx.x;
  const float L2E = 1.4426950408889634f, LN2 = 0.6931471805599453f;

  float np = 0.f;
  for (int s = lane; s < 512; s += 64) {
    const int tg = tags[b * 512 + s];
    np += em[((size_t)b * 512 + s) * 9 + tg];
    if (s > 0) np += tr[tags[b * 512 + s - 1] * 9 + tg];
  }
#pragma unroll
  for (int off = 32; off > 0; off >>= 1) np += __shfl_down(np, off);

  const int j = (lane < 9) ? lane : 0;
  float tcol[9];
#pragma unroll
  for (int i = 0; i < 9; i++) tcol[i] = tr[i * 9 + j];
  float alpha = st[j] + em[((size_t)b * 512 + 0) * 9 + j];
  for (int s = 1; s < 512; s++) {
    float abc[9];
#pragma unroll
    for (int i = 0; i < 9; i++) abc[i] = __shfl(alpha, i) + tcol[i];
    float mx = abc[0];
#pragma unroll
    for (int i = 1; i < 9; i++) mx = fmaxf(mx, abc[i]);
    float sm = 0.f;
#pragma unroll
    for (int i = 0; i < 9; i++) sm += exp2f((abc[i] - mx) * L2E);
    alpha = mx + log2f(sm) * LN2 + em[((size_t)b * 512 + s) * 9 + j];
  }
  float v = (lane < 9) ? (alpha + et[j]) : -3.0e38f;
  float mx = v;
#pragma unroll
  for (int off = 32; off > 0; off >>= 1) mx = fmaxf(mx, __shfl_xor(mx, off));
  float se = (lane < 9) ? exp2f((v - mx) * L2E) : 0.f;
#pragma unroll
  for (int off = 32; off > 0; off >>= 1) se += __shfl_xor(se, off);
  const float denom = mx + log2f(se) * LN2;

  if (lane == 0) {
    const float num = np + st[tags[b * 512]] + et[tags[b * 512 + 511]];
    atomicAdd(loss, num - denom);
  }
}

__global__ void k_final(const float* __restrict__ loss, float* __restrict__ out) {
  out[0] = -loss[0] * (1.f / 64.f);
}

// ---------------------------------------------------------------------------
extern "C" void kernel_launch(void* const* d_in, const int* in_sizes, int n_in,
                              void* d_out, int out_size, void* d_ws, size_t ws_size,
                              hipStream_t stream) {
  (void)in_sizes; (void)n_in; (void)out_size; (void)ws_size;
  const int*   sentence = (const int*)d_in[0];
  const int*   tags     = (const int*)d_in[1];
  const float* emb      = (const float*)d_in[2];
  const float* w_ih_f   = (const float*)d_in[3];
  const float* w_hh_f   = (const float*)d_in[4];
  const float* b_ih_f   = (const float*)d_in[5];
  const float* b_hh_f   = (const float*)d_in[6];
  const float* w_ih_b   = (const float*)d_in[7];
  const float* w_hh_b   = (const float*)d_in[8];
  const float* b_ih_b   = (const float*)d_in[9];
  const float* b_hh_b   = (const float*)d_in[10];
  const float* w_lin    = (const float*)d_in[11];
  const float* b_lin    = (const float*)d_in[12];
  const float* start_t  = (const float*)d_in[13];
  const float* end_t    = (const float*)d_in[14];
  const float* trans    = (const float*)d_in[15];
  const float* h0       = (const float*)d_in[16];
  const float* c0       = (const float*)d_in[17];

  char* ws = (char*)d_ws;
  unsigned short* XWr = (unsigned short*)(ws + XWR_OFF);
  unsigned short* X   = (unsigned short*)(ws + X_OFF);
  unsigned short* HS  = (unsigned short*)(ws + HS_OFF);
  unsigned short* WIH = (unsigned short*)(ws + WIH_OFF);
  unsigned short* WHH = (unsigned short*)(ws + WHH_OFF);
  float*          BIAS= (float*)(ws + BIAS_OFF);
  float*          EM  = (float*)(ws + EM_OFF);
  // X region is dead after k_gemm -> loss (64 B) + 4-buffer h exchange (512 KB)
  float*          LOSS= (float*)(ws + X_OFF);
  unsigned short* HG4 = (unsigned short*)(ws + X_OFF + 4096);

  k_gather<<<32768, 128, 0, stream>>>(sentence, emb, X);
  k_prep<<<4096, 128, 0, stream>>>(w_ih_f, w_hh_f, b_ih_f, b_hh_f,
                                   w_ih_b, w_hh_b, b_ih_b, b_hh_b, WIH, WHH, BIAS);
  k_gemm<<<dim3(32, 256), 256, 0, stream>>>(X, WIH, BIAS, XWr);
  // X consumed; now safe to build loss + h buffers in its place
  hipMemsetAsync(LOSS, 0, 64, stream);
  k_inith<<<64, 256, 0, stream>>>(h0, HG4);
  k_lstm<<<64, 256, 0, stream>>>(WHH, XWr, c0, HG4, HS);
  k_emis<<<8192, 256, 0, stream>>>(HS, w_lin, b_lin, EM);
  k_crf<<<64, 64, 0, stream>>>(EM, tags, start_t, end_t, trans, LOSS);
  k_final<<<1, 1, 0, stream>>>(LOSS, (float*)d_out);
}